// Round 25
// baseline (279.378 us; speedup 1.0000x reference)
//
#include <hip/hip_runtime.h>

// DCMHAttention on MI355X (gfx950). Round 24: qkv GEMM re-tiled 128x256,
// BK=32, 512thr/8 waves, LDS 48KB -> 432 blocks, 2 independent blocks/CU
// (stall interleave; the 256^2 single-block config lockstepped the whole CU).
// BK=32 k-rows are 64B: two matrix rows packed per 128B LDS row so the
// (row&7)<<4 swizzle stays 2-way-free. Counted vmcnt(3), 2 barriers/tile.
// Rest = R24 best (LDS transpose-reduce proj, bf16 L, restricted P writes).
// B=2 T=1024 D=2048 H=16 HD=128 K=128 IH=1.

typedef unsigned short u16;
typedef unsigned int u32;
typedef __attribute__((ext_vector_type(8))) short s16x8;   // 8 x bf16 MFMA frag
typedef __attribute__((ext_vector_type(4))) float f32x4;   // MFMA accum
typedef __attribute__((ext_vector_type(2))) float f32x2;
typedef __attribute__((ext_vector_type(2))) u16 u16x2;
typedef __attribute__((ext_vector_type(8))) u16 u16x8;

#define DEV __device__ __forceinline__

DEV float bf2f(u16 u) { union { u32 u; float f; } a; a.u = ((u32)u) << 16; return a.f; }
DEV u16 f2bf(float f) {
  union { float f; u32 u; } a; a.f = f;
  u32 r = a.u + 0x7fffu + ((a.u >> 16) & 1u);   // RNE
  return (u16)(r >> 16);
}

DEV void gload16(const void* g, void* l) {
  __builtin_amdgcn_global_load_lds((__attribute__((address_space(1))) void*)g,
                                   (__attribute__((address_space(3))) void*)l,
                                   16, 0, 0);
}

// ---------------------------------------------------------------------------
// 128x256 pipelined GEMM: C = A (MxK) * B^T (B given [N][K]). BK=32.
// 512 threads = 8 waves (2M x 4N), per-wave 64x64 (acc[4][4]).
// LDS 48KB: double-buffered A(8KB),B(16KB); BK=32 rows are 64B, packed two
// matrix rows per 128B LDS row, XOR-swizzled byte ^= (ldsrow&7)<<4 within the
// 128B row (2-way bank aliasing = free). Counted vmcnt(3), 2 barriers/tile.
// Grid (N/256, M/128), total blocks % 8 == 0 (XCD swizzle). 2 blocks/CU.
// ---------------------------------------------------------------------------
template <int OUTBF>
__global__ __launch_bounds__(512, 2) void gemm256(
    const u16* __restrict__ A, const u16* __restrict__ B, void* __restrict__ Cp,
    int K, int lda, int ldb, int ldc)
{
  __shared__ u16 sA[2][128 * 32];   // 8KB per buffer
  __shared__ u16 sB[2][256 * 32];   // 16KB per buffer
  const int tid = threadIdx.x, ln = tid & 63;
  const int wid = tid >> 6, wm = wid >> 2, wn = wid & 3;

  const int nx = gridDim.x;
  const int fid = blockIdx.y * nx + blockIdx.x;
  const int cpx = (nx * gridDim.y) >> 3;
  const int nid = (fid & 7) * cpx + (fid >> 3);
  const int bx = nid % nx, by = nid / nx;

  const u16* Ab = A + (size_t)(by * 128) * lda;
  const u16* Bb = B + (size_t)(bx * 256) * ldb;

  f32x4 acc[4][4];
#pragma unroll
  for (int m = 0; m < 4; ++m)
#pragma unroll
    for (int n = 0; n < 4; ++n) {
      f32x4 zz = {0.f, 0.f, 0.f, 0.f};
      acc[m][n] = zz;
    }

  // staging addressing: LDS linear o=chunk*8192+tid*16; ldsrow=o>>7 (128B
  // rows = 2 matrix rows of 64B); inverse-swizzled global source.
  int saro, sarow, sacol;              // A: 1 chunk (8KB / 512thr)
  {
    int o = tid * 16;
    saro = o;
    int r = o >> 7;
    int swz = (o & 127) ^ ((r & 7) << 4);
    sarow = 2 * r + (swz >> 6);
    sacol = (swz & 63) >> 1;
  }
  int sbro[2], sbrow[2], sbcol[2];     // B: 2 chunks (16KB)
#pragma unroll
  for (int i = 0; i < 2; ++i) {
    int o = i * 8192 + tid * 16;
    sbro[i] = o;
    int r = o >> 7;
    int swz = (o & 127) ^ ((r & 7) << 4);
    sbrow[i] = 2 * r + (swz >> 6);
    sbcol[i] = (swz & 63) >> 1;
  }

#define STAGE_A(ba, k0)                                                   \
  gload16(Ab + (size_t)sarow * lda + (k0) + sacol, (char*)(ba) + saro);
#define STAGE_B(bb, k0)                                                   \
  {                                                                       \
    _Pragma("unroll")                                                     \
    for (int i_ = 0; i_ < 2; ++i_)                                        \
      gload16(Bb + (size_t)sbrow[i_] * ldb + (k0) + sbcol[i_],            \
              (char*)(bb) + sbro[i_]);                                    \
  }

  // read addressing: matrix row R -> ldsrow R>>1, half (R&1)*64, swizzled.
  const int kbyte = (ln >> 4) * 16;       // 16B slot within 64B k-row
  const int arw = wm * 64 + (ln & 15);    // + m*16
  const int brw = wn * 64 + (ln & 15);    // + n*16
  const int NT = K >> 5;

#define RD(p, R)                                                          \
  (*(const s16x8*)((const char*)(p) + (size_t)((R) >> 1) * 128 +          \
                   ((((R) & 1) * 64 + kbyte) ^ ((((R) >> 1) & 7) << 4))))

  // prologue: stage tiles 0 and 1 (6 loads in flight)
  STAGE_A(sA[0], 0); STAGE_B(sB[0], 0);
  STAGE_A(sA[1], 32); STAGE_B(sB[1], 32);

  for (int t = 0; t < NT; ++t) {
    const int c = t & 1;
    // tile t's 3 loads done when <=3 outstanding (tile t+1's in flight)
    asm volatile("s_waitcnt vmcnt(3)" ::: "memory");
    __builtin_amdgcn_s_barrier();
    const u16* pa = sA[c];
    const u16* pb = sB[c];
    s16x8 bfr[4];
#pragma unroll
    for (int n = 0; n < 4; ++n)
      bfr[n] = RD(pb, brw + n * 16);
#pragma unroll
    for (int m = 0; m < 4; ++m) {
      s16x8 afr = RD(pa, arw + m * 16);
      __builtin_amdgcn_s_setprio(1);
#pragma unroll
      for (int n = 0; n < 4; ++n)
        acc[m][n] = __builtin_amdgcn_mfma_f32_16x16x32_bf16(afr, bfr[n], acc[m][n], 0, 0, 0);
      __builtin_amdgcn_s_setprio(0);
    }
    // all waves consumed buf c -> overwrite with tile t+2
    __builtin_amdgcn_s_barrier();
    if (t + 2 < NT) { STAGE_A(sA[c], (t + 2) * 32); STAGE_B(sB[c], (t + 2) * 32); }
  }
#undef STAGE_A
#undef STAGE_B
#undef RD

  const int r0 = by * 128 + wm * 64 + ((ln >> 4) << 2);
  const int c0 = bx * 256 + wn * 64 + (ln & 15);
#pragma unroll
  for (int m = 0; m < 4; ++m)
#pragma unroll
    for (int n = 0; n < 4; ++n)
#pragma unroll
      for (int j = 0; j < 4; ++j) {
        int row = r0 + m * 16 + j, col = c0 + n * 16;
        if (OUTBF)
          ((u16*)Cp)[(size_t)row * ldc + col] = f2bf(acc[m][n][j]);
        else
          ((float*)Cp)[(size_t)row * ldc + col] = acc[m][n][j];
      }
}

// ---------------------------------------------------------------------------
// Generic batched GEMM (128x128 tile) — unchanged proven kernel.
// ---------------------------------------------------------------------------
template <int OUTBF>
__global__ __launch_bounds__(256) void gemm_bt(
    const u16* __restrict__ A, const u16* __restrict__ B, void* __restrict__ Cp,
    int K, int lda, int ldb, int ldc,
    long sAb, long sBb, long sCb1, long sCb2, int CZ2, int cmode, int swz)
{
  int bx = blockIdx.x, by = blockIdx.y;
  if (swz) {
    int nx = gridDim.x;
    int fid = by * nx + bx;
    int cpx = (nx * gridDim.y) >> 3;
    int nid = (fid & 7) * cpx + (fid >> 3);
    bx = nid % nx; by = nid / nx;
  }
  if (cmode == 1 && bx > by) return;
  __shared__ u16 sA[128 * 64];
  __shared__ u16 sB[128 * 64];
  const int tid = threadIdx.x, wv = tid >> 6, ln = tid & 63;
  const int z = blockIdx.z;
  const u16* Ab = A + (size_t)z * sAb + (size_t)(by * 128) * lda;
  const u16* Bb = B + (size_t)z * sBb + (size_t)(bx * 128) * ldb;
  const int wr = (wv >> 1) * 64, wc = (wv & 1) * 64;
  const int Keff = (cmode == 2) ? min(K, (by + 1) * 128) : K;

  f32x4 acc[4][4];
#pragma unroll
  for (int m = 0; m < 4; ++m)
#pragma unroll
    for (int n = 0; n < 4; ++n) {
      f32x4 zz = {0.f, 0.f, 0.f, 0.f};
      acc[m][n] = zz;
    }

  int o_[4], r_[4], cb_[4];
#pragma unroll
  for (int i = 0; i < 4; ++i) {
    int o = (wv * 4 + i) * 1024 + ln * 16;
    o_[i] = o;
    int r = o >> 7;
    r_[i] = r;
    cb_[i] = (o & 127) ^ ((r & 7) << 4);
  }
  const int frswz = (ln & 7) << 4;
  const int fkcol = (ln >> 4) << 4;

  for (int k0 = 0; k0 < Keff; k0 += 64) {
    __syncthreads();
#pragma unroll
    for (int i = 0; i < 4; ++i)
      gload16(Ab + (size_t)r_[i] * lda + (k0 + (cb_[i] >> 1)), (char*)sA + o_[i]);
#pragma unroll
    for (int i = 0; i < 4; ++i)
      gload16(Bb + (size_t)r_[i] * ldb + (k0 + (cb_[i] >> 1)), (char*)sB + o_[i]);
    __syncthreads();

#pragma unroll
    for (int ks = 0; ks < 2; ++ks) {
      s16x8 av[4], bv[4];
#pragma unroll
      for (int m = 0; m < 4; ++m) {
        int row = wr + m * 16 + (ln & 15);
        int addr = row * 128 + ((ks * 64 + fkcol) ^ frswz);
        av[m] = *(const s16x8*)((const char*)sA + addr);
      }
#pragma unroll
      for (int n = 0; n < 4; ++n) {
        int row = wc + n * 16 + (ln & 15);
        int addr = row * 128 + ((ks * 64 + fkcol) ^ frswz);
        bv[n] = *(const s16x8*)((const char*)sB + addr);
      }
#pragma unroll
      for (int m = 0; m < 4; ++m)
#pragma unroll
        for (int n = 0; n < 4; ++n)
          acc[m][n] = __builtin_amdgcn_mfma_f32_16x16x32_bf16(av[m], bv[n], acc[m][n], 0, 0, 0);
    }
  }

  const size_t cbase = (size_t)(z / CZ2) * sCb1 + (size_t)(z % CZ2) * sCb2;
  const int r0 = by * 128 + wr + ((ln >> 4) << 2);
  const int c0 = bx * 128 + wc + (ln & 15);
#pragma unroll
  for (int m = 0; m < 4; ++m)
#pragma unroll
    for (int n = 0; n < 4; ++n)
#pragma unroll
      for (int j = 0; j < 4; ++j) {
        int row = r0 + m * 16 + j, col = c0 + n * 16;
        if (OUTBF)
          ((u16*)Cp)[cbase + (size_t)row * ldc + col] = f2bf(acc[m][n][j]);
        else
          ((float*)Cp)[cbase + (size_t)row * ldc + col] = acc[m][n][j];
      }
}

// ---------------------------------------------------------------------------
// Transpose (batched): dst[z][c][r] = src[z1*sSrc1+z2*sSrc2 + r*srcLd + c]
// INBF=0: f32 source; INBF=1: bf16 source. Output bf16, rows padded to Cpad.
// ---------------------------------------------------------------------------
template <int INBF>
__global__ __launch_bounds__(256) void transpose_to_bf16(
    const void* __restrict__ srcv, u16* __restrict__ dst,
    int R, int C, int Cpad, int srcLd, long sSrc1, long sSrc2, int Z2, long sDst)
{
  __shared__ float tile[32][33];
  const int z = blockIdx.z, z1 = z / Z2, z2 = z % Z2;
  const size_t sbase = (size_t)z1 * sSrc1 + (size_t)z2 * sSrc2;
  u16* d = dst + (size_t)z * sDst;
  const int c0 = blockIdx.x * 32, r0 = blockIdx.y * 32;
  const int tx = threadIdx.x, ty = threadIdx.y;
#pragma unroll
  for (int i = 0; i < 4; ++i) {
    int r = r0 + ty + i * 8, c = c0 + tx;
    float v = 0.f;
    if (c < C && r < R) {
      if (INBF) v = bf2f(((const u16*)srcv)[sbase + (size_t)r * srcLd + c]);
      else      v = ((const float*)srcv)[sbase + (size_t)r * srcLd + c];
    }
    tile[ty + i * 8][tx] = v;
  }
  __syncthreads();
#pragma unroll
  for (int i = 0; i < 4; ++i) {
    int dr = c0 + ty + i * 8, dc = r0 + tx;
    if (dr < Cpad && dc < R) d[(size_t)dr * R + dc] = f2bf(tile[tx][ty + i * 8]);
  }
}

__global__ void cvt_f32_bf16_k(const float* __restrict__ src, u16* __restrict__ dst, int n4) {
  int i = blockIdx.x * 256 + threadIdx.x;
  if (i >= n4) return;
  const float4 v = ((const float4*)src)[i];
  u16* o = dst + (size_t)i * 4;
  o[0] = f2bf(v.x); o[1] = f2bf(v.y); o[2] = f2bf(v.z); o[3] = f2bf(v.w);
}

// RoPE from bf16 qkvm (row stride 6912): reads split halves, writes interleaved.
__global__ __launch_bounds__(256) void rope_k(
    const u16* __restrict__ qkvm, const float* __restrict__ fc,
    u16* __restrict__ qb, u16* __restrict__ kb)
{
  const int bt = blockIdx.x, b = bt >> 10, t = bt & 1023;
  const u16* row = qkvm + (size_t)bt * 6912;
  const float SC = 0.08838834764831845f;  // 128^-0.5
#pragma unroll
  for (int it = 0; it < 4; ++it) {
    int idx = threadIdx.x + it * 256;
    int h = idx >> 6, j = idx & 63;
    float c = fc[(t * 64 + j) * 2], sn = fc[(t * 64 + j) * 2 + 1];
    float qa = bf2f(row[h * 128 + j]), qbv = bf2f(row[h * 128 + 64 + j]);
    float ka = bf2f(row[2048 + h * 128 + j]), kbv = bf2f(row[2048 + h * 128 + 64 + j]);
    size_t o = ((size_t)(b * 16 + h) * 1024 + t) * 128 + 2 * j;
    qb[o]     = f2bf((qa * c - qbv * sn) * SC);
    qb[o + 1] = f2bf((qbv * c + qa * sn) * SC);
    kb[o]     = f2bf(ka * c - kbv * sn);
    kb[o + 1] = f2bf(kbv * c + ka * sn);
  }
}

// gelu in-place on bf16 hidden cols 6144..6655 of qkvm rows (stride 6912)
__global__ __launch_bounds__(64) void gelu_bf16_k(u16* __restrict__ qm) {
  int bt = blockIdx.x, tid = threadIdx.x;
  u16* p = qm + (size_t)bt * 6912 + 6144 + tid * 8;
  u16x8 v = *(u16x8*)p;
#pragma unroll
  for (int i = 0; i < 8; ++i) {
    float f = bf2f(v[i]);
    f = 0.5f * f * (1.f + erff(f * 0.70710678118654752f));
    v[i] = f2bf(f);
  }
  *(u16x8*)p = v;
}

// w = einsum(hid[bt,c,k], qkw[c,k,i,m]); w1 rms-normed over m. One wave per bt.
__global__ __launch_bounds__(64) void wproj_k(
    const u16* __restrict__ qkvm, const float* __restrict__ qkw,
    float* __restrict__ w1a, float* __restrict__ w2a, float* __restrict__ kpT)
{
  const int bt = blockIdx.x, ln = threadIdx.x;
  const int c = ln >> 4, m = ln & 15;
  const int b = bt >> 10, t = bt & 1023;
  const u16* hp = qkvm + (size_t)bt * 6912 + 6144 + c * 128;
  const float* Wp = qkw + (size_t)c * 4096 + m;
  float w1 = 0.f, w2 = 0.f;
  for (int k = 0; k < 128; ++k) {
    float hv = bf2f(hp[k]);
    w1 += hv * Wp[k * 32];
    w2 += hv * Wp[k * 32 + 16];
  }
  float ss = w1 * w1;
  ss += __shfl_xor(ss, 1); ss += __shfl_xor(ss, 2);
  ss += __shfl_xor(ss, 4); ss += __shfl_xor(ss, 8);
  float nrm = rsqrtf(ss * (1.f / 16.f) + 1e-6f);
  float w1n = w1 * nrm;
  size_t o = (size_t)bt * 64 + c * 16 + m;
  w1a[o] = w1n;
  w2a[o] = w2;
  size_t kb = (size_t)b * 98304 + (size_t)m * 1024 + t;
  if (c == 1) { kpT[kb] = w1n; kpT[kb + 16384] = w2; }
  if (c == 3) { kpT[kb + 49152] = w1n; kpT[kb + 65536] = w2; }
}

// dd from bf16 cols 6656..6719 of qkvm (stride 6912)
__global__ __launch_bounds__(64) void dd_k(const u16* __restrict__ qkvm,
                                           float* __restrict__ dda, float* __restrict__ kpT) {
  int bt = blockIdx.x, ln = threadIdx.x;
  int c = ln >> 4, m = ln & 15;
  int b = bt >> 10, t = bt & 1023;
  float v = tanhf(bf2f(qkvm[(size_t)bt * 6912 + 6656 + ln]));
  dda[(size_t)bt * 64 + ln] = v;
  size_t kb = (size_t)b * 98304 + (size_t)m * 1024 + t;
  if (c == 1) kpT[kb + 32768] = v;
  if (c == 3) kpT[kb + 81920] = v;
}

// ---------------------------------------------------------------------------
// Fused: preproj(cross-head) -> causal mask -> softmax (no max; logits O(15))
// -> postproj -> P(bf16). L bf16. One block per (b,t); 512 threads x
// 2 s-cols x 16 heads. Sum-reduce: wave-local LDS transpose (stride-17 pad,
// conflict-free) + 2 shfl. P stores skipped for s0 >= (t/128+1)*128.
// ---------------------------------------------------------------------------
__global__ __launch_bounds__(512, 4) void proj_softmax_k(
    const u16* __restrict__ L, u16* __restrict__ P,
    const float* __restrict__ w1a, const float* __restrict__ w2a,
    const float* __restrict__ dda, const float* __restrict__ kparT)
{
  const int t = blockIdx.x, b = blockIdx.y;
  const int tid = threadIdx.x, wv = tid >> 6, ln = tid & 63;
  const int s0 = tid * 2;
  const bool live = (s0 <= t);
  const int sKeff = (t & ~127) + 128;   // PV reads s in [0, sKeff)

  __shared__ float tbuf[8][64][17];     // stride-17: scalar ds ops conflict-free
  __shared__ float qpar[6][16];
  __shared__ float red2[16][8];
  __shared__ float rzf[16];
  if (tid < 96) {
    int a = tid >> 4, hh = tid & 15;
    const float* sp = (a == 0 || a == 3) ? w1a : ((a == 1 || a == 4) ? w2a : dda);
    int cc = (a < 3) ? 0 : 2;
    qpar[a][hh] = sp[(size_t)(b * 1024 + t) * 64 + cc * 16 + hh];
  }
  __syncthreads();

  const float* kp = kparT + (size_t)b * 98304 + s0;
  float v[16][2];
  const size_t lbase = ((size_t)(b * 16) * 1024 + t) * 1024 + s0;

  if (live) {
#pragma unroll
    for (int h = 0; h < 16; ++h) {
      u16x2 d = *(const u16x2*)(L + lbase + (size_t)h * 1048576);
      v[h][0] = bf2f(d[0]); v[h][1] = bf2f(d[1]);
    }
    float dq0 = 0.f, dq1 = 0.f, dk0 = 0.f, dk1 = 0.f;
#pragma unroll
    for (int h = 0; h < 16; ++h) {
      f32x2 k1 = *(const f32x2*)(kp + h * 1024);
      dq0 += v[h][0] * qpar[0][h]; dq1 += v[h][1] * qpar[0][h];
      dk0 += v[h][0] * k1[0];      dk1 += v[h][1] * k1[1];
    }
    const bool ok1 = (s0 + 1 <= t);
#pragma unroll
    for (int h = 0; h < 16; ++h) {
      f32x2 k2 = *(const f32x2*)(kp + 16384 + h * 1024);
      f32x2 kd = *(const f32x2*)(kp + 32768 + h * 1024);
      float a0 = v[h][0] * (1.f + qpar[2][h] + kd[0]) + qpar[1][h] * dq0 + k2[0] * dk0;
      float a1 = v[h][1] * (1.f + qpar[2][h] + kd[1]) + qpar[1][h] * dq1 + k2[1] * dk1;
      v[h][0] = __expf(a0);
      v[h][1] = ok1 ? __expf(a1) : 0.f;
    }
  }

  // wave-local LDS transpose reduce (same-wave ds ordering; no barrier).
  {
    float* tb = &tbuf[wv][ln][0];
#pragma unroll
    for (int h = 0; h < 16; ++h)
      tb[h] = live ? (v[h][0] + v[h][1]) : 0.f;
    int hh = ln & 15, q = ln >> 4;
    float sum = 0.f;
#pragma unroll
    for (int k = 0; k < 16; ++k) sum += tbuf[wv][q * 16 + k][hh];
    sum += __shfl_xor(sum, 16);
    sum += __shfl_xor(sum, 32);
    if (ln < 16) red2[ln][wv] = sum;
  }
  __syncthreads();
  if (tid < 16)
    rzf[tid] = 1.f / (((red2[tid][0] + red2[tid][1]) + (red2[tid][2] + red2[tid][3])) +
                      ((red2[tid][4] + red2[tid][5]) + (red2[tid][6] + red2[tid][7])));
  __syncthreads();

  if (s0 >= sKeff) return;   // PV never reads this region (no barriers below)

  // post-projection + store P (bf16). Masked -> exactly 0.
  const size_t pbase = ((size_t)(b * 16) * 1024 + t) * 1024 + s0;
  if (live) {
    float pdq0 = 0.f, pdq1 = 0.f, pdk0 = 0.f, pdk1 = 0.f;
#pragma unroll
    for (int h = 0; h < 16; ++h) {
      float rz = rzf[h];
      f32x2 k1 = *(const f32x2*)(kp + 49152 + h * 1024);
      float p0 = v[h][0] * rz, p1 = v[h][1] * rz;
      v[h][0] = p0; v[h][1] = p1;
      pdq0 += p0 * qpar[3][h]; pdq1 += p1 * qpar[3][h];
      pdk0 += p0 * k1[0];      pdk1 += p1 * k1[1];
    }
#pragma unroll
    for (int h = 0; h < 16; ++h) {
      f32x2 k2 = *(const f32x2*)(kp + 65536 + h * 1024);
      f32x2 kd = *(const f32x2*)(kp + 81920 + h * 1024);
      u16x2 pk;
      pk[0] = f2bf(v[h][0] * (1.f + qpar[5][h] + kd[0]) + qpar[4][h] * pdq0 + k2[0] * pdk0);
      pk[1] = f2bf(v[h][1] * (1.f + qpar[5][h] + kd[1]) + qpar[4][h] * pdq1 + k2[1] * pdk1);
      *(u16x2*)(P + pbase + (size_t)h * 1048576) = pk;
    }
  } else {
    u16x2 z2 = {0, 0};
#pragma unroll
    for (int h = 0; h < 16; ++h)
      *(u16x2*)(P + pbase + (size_t)h * 1048576) = z2;
  }
}

// ---------------------------------------------------------------------------
extern "C" void kernel_launch(void* const* d_in, const int* in_sizes, int n_in,
                              void* d_out, int out_size, void* d_ws, size_t ws_size,
                              hipStream_t stream)
{
  (void)in_sizes; (void)n_in; (void)out_size; (void)ws_size;
  const float* x    = (const float*)d_in[0];
  const float* fc   = (const float*)d_in[2];
  const float* wqkv = (const float*)d_in[3];
  const float* wo   = (const float*)d_in[4];
  const float* dw1  = (const float*)d_in[5];
  const float* qkw  = (const float*)d_in[6];
  const float* ddw  = (const float*)d_in[7];
  float* out = (float*)d_out;
  char* w = (char*)d_ws;

  // persistent region
  u16*   woT   = (u16*)(w + 0);
  u16*   qb    = (u16*)(w + 8388608);
  u16*   kb    = (u16*)(w + 16777216);
  u16*   vT    = (u16*)(w + 25165824);
  u16*   obf   = (u16*)(w + 33554432);
  float* w1a   = (float*)(w + 41943040);
  float* w2a   = (float*)(w + 42467328);
  float* dda   = (float*)(w + 42991616);
  const size_t TB = 43515904;
  // transient layout A (dead before attention phase)
  u16*   xb    = (u16*)(w + TB);                       // 8 MB
  u16*   wallT = (u16*)(w + TB + 8388608);             // [6912][2048] bf16 = 28.3 MB
  u16*   qkvm  = (u16*)(w + TB + 36700160);            // [2048][6912] bf16 = 28.3 MB
  // transient layout B (attention) overlays layout A
  u16*   L     = (u16*)(w + TB);                       // bf16 logits, 64 MB
  u16*   P     = (u16*)(w + TB + 67108864);            // bf16 probs, 64 MB
  float* kparT = (float*)(w + 244842496);              // 768 KiB
  // total ws need: 245,628,928 bytes

  // input converts / transposes (to bf16, B^T layouts; wqkv|dw1|ddw merged,
  // ddw segment zero-padded to row 6912 via Cpad=256)
  cvt_f32_bf16_k<<<4096, 256, 0, stream>>>(x, xb, 1048576);
  transpose_to_bf16<0><<<dim3(192, 64, 1), dim3(32, 8), 0, stream>>>(wqkv, wallT, 2048, 6144, 6144, 6144, 0, 0, 1, 0);
  transpose_to_bf16<0><<<dim3(16, 64, 1),  dim3(32, 8), 0, stream>>>(dw1,  wallT + (size_t)6144 * 2048, 2048, 512, 512, 512, 0, 0, 1, 0);
  transpose_to_bf16<0><<<dim3(8, 64, 1),   dim3(32, 8), 0, stream>>>(ddw,  wallT + (size_t)6656 * 2048, 2048, 64, 256, 64, 0, 0, 1, 0);
  transpose_to_bf16<0><<<dim3(64, 64, 1),  dim3(32, 8), 0, stream>>>(wo,   woT, 2048, 2048, 2048, 2048, 0, 0, 1, 0);

  // merged qkv|hidden|ddraw GEMM (M=2048, N=6912, K=2048; 128x256 BK=32)
  gemm256<1><<<dim3(27, 16, 1), 512, 0, stream>>>(xb, wallT, qkvm, 2048, 2048, 2048, 6912);
  rope_k<<<2048, 256, 0, stream>>>(qkvm, fc, qb, kb);
  transpose_to_bf16<1><<<dim3(4, 32, 32), dim3(32, 8), 0, stream>>>(qkvm + 4096, vT, 1024, 128, 128, 6912, 7077888, 128, 16, 131072);

  // dynamic-compose weights from merged buffer
  gelu_bf16_k<<<2048, 64, 0, stream>>>(qkvm);
  wproj_k<<<2048, 64, 0, stream>>>(qkvm, qkw, w1a, w2a, kparT);
  dd_k<<<2048, 64, 0, stream>>>(qkvm, dda, kparT);

  // attention (L in bf16)
  gemm_bt<1><<<dim3(8, 8, 32), 256, 0, stream>>>(qb, kb, L, 128, 128, 128, 1024, 131072, 131072, 1048576, 0, 1, 1, 0);
  proj_softmax_k<<<dim3(1024, 2, 1), 512, 0, stream>>>(L, P, w1a, w2a, dda, kparT);
  gemm_bt<1><<<dim3(1, 8, 32), 256, 0, stream>>>(P, vT, obf, 1024, 1024, 1024, 2048, 1048576, 131072, 2097152, 128, 16, 2, 0);

  // out = o @ wo (XCD-swizzled, 128^2)
  gemm_bt<0><<<dim3(16, 16, 1), 256, 0, stream>>>(obf, woT, out, 2048, 2048, 2048, 2048, 0, 0, 0, 0, 1, 0, 1);
}

// Round 26
// 270.394 us; speedup vs baseline: 1.0332x; 1.0332x over previous
//
#include <hip/hip_runtime.h>

// DCMHAttention on MI355X (gfx950). Round 25: revert gemm256 to the R24
// measured-best (256^2, BK=64, 1024thr/16 waves, 2-barrier counted-vmcnt;
// 71us, total 271.9us). R25's 128x256/BK=32 retile doubled sync frequency
// per K and regressed (76us). Rest = R24 best throughout.
// B=2 T=1024 D=2048 H=16 HD=128 K=128 IH=1.

typedef unsigned short u16;
typedef unsigned int u32;
typedef __attribute__((ext_vector_type(8))) short s16x8;   // 8 x bf16 MFMA frag
typedef __attribute__((ext_vector_type(4))) float f32x4;   // MFMA accum
typedef __attribute__((ext_vector_type(2))) float f32x2;
typedef __attribute__((ext_vector_type(2))) u16 u16x2;
typedef __attribute__((ext_vector_type(8))) u16 u16x8;

#define DEV __device__ __forceinline__

DEV float bf2f(u16 u) { union { u32 u; float f; } a; a.u = ((u32)u) << 16; return a.f; }
DEV u16 f2bf(float f) {
  union { float f; u32 u; } a; a.f = f;
  u32 r = a.u + 0x7fffu + ((a.u >> 16) & 1u);   // RNE
  return (u16)(r >> 16);
}

DEV void gload16(const void* g, void* l) {
  __builtin_amdgcn_global_load_lds((__attribute__((address_space(1))) void*)g,
                                   (__attribute__((address_space(3))) void*)l,
                                   16, 0, 0);
}

// ---------------------------------------------------------------------------
// 256x256 deep-pipelined GEMM: C = A (MxK) * B^T (B given [N][K]).
// 1024 threads = 16 waves (4M x 4N), per-wave 64x64 output (acc[4][4]). BK=64.
// LDS 128KB double-buffered, XOR-swizzled (byte ^= (row&7)<<4).
// Counted-vmcnt pipeline, 2 barriers/tile: {vmcnt(4); barrier; ds_read frags
// + 32 MFMA (setprio-wrapped); barrier; stage t+2}. Grid blocks % 8 == 0.
// ---------------------------------------------------------------------------
template <int OUTBF>
__global__ __launch_bounds__(1024, 1) void gemm256(
    const u16* __restrict__ A, const u16* __restrict__ B, void* __restrict__ Cp,
    int K, int lda, int ldb, int ldc)
{
  __shared__ u16 sA[2][256 * 64];
  __shared__ u16 sB[2][256 * 64];
  const int tid = threadIdx.x, ln = tid & 63;
  const int wid = tid >> 6, wm = wid >> 2, wn = wid & 3;

  const int nx = gridDim.x;
  const int fid = blockIdx.y * nx + blockIdx.x;
  const int cpx = (nx * gridDim.y) >> 3;
  const int nid = (fid & 7) * cpx + (fid >> 3);
  const int bx = nid % nx, by = nid / nx;

  const u16* Ab = A + (size_t)(by * 256) * lda;
  const u16* Bb = B + (size_t)(bx * 256) * ldb;

  f32x4 acc[4][4];
#pragma unroll
  for (int m = 0; m < 4; ++m)
#pragma unroll
    for (int n = 0; n < 4; ++n) {
      f32x4 zz = {0.f, 0.f, 0.f, 0.f};
      acc[m][n] = zz;
    }

  int srow[2], scol[2], soff[2];
#pragma unroll
  for (int i = 0; i < 2; ++i) {
    int o = i * 16384 + tid * 16;
    soff[i] = o;
    int r = o >> 7;              // 128B per row (64 bf16)
    srow[i] = r;
    scol[i] = ((o & 127) ^ ((r & 7) << 4)) >> 1;
  }

#define STAGE_A(ba, k0)                                                   \
  {                                                                       \
    _Pragma("unroll")                                                     \
    for (int i_ = 0; i_ < 2; ++i_)                                        \
      gload16(Ab + (size_t)srow[i_] * lda + (k0) + scol[i_],              \
              (char*)(ba) + soff[i_]);                                    \
  }
#define STAGE_B(bb, k0)                                                   \
  {                                                                       \
    _Pragma("unroll")                                                     \
    for (int i_ = 0; i_ < 2; ++i_)                                        \
      gload16(Bb + (size_t)srow[i_] * ldb + (k0) + scol[i_],              \
              (char*)(bb) + soff[i_]);                                    \
  }

  const int arow = wm * 64 + (ln & 15);    // + ph*16
  const int brow = wn * 64 + (ln & 15);    // + n*16
  const int kb = (ln >> 4) * 16;           // byte offset within 64B kk-half
  const int frswz = (ln & 7) << 4;         // read-side swizzle
  const int NT = K >> 6;

  // prologue: stage tiles 0 and 1 (8 loads in flight)
  STAGE_A(sA[0], 0); STAGE_B(sB[0], 0);
  STAGE_A(sA[1], 64); STAGE_B(sB[1], 64);

  for (int t = 0; t < NT; ++t) {
    const int c = t & 1;
    asm volatile("s_waitcnt vmcnt(4)" ::: "memory");
    __builtin_amdgcn_s_barrier();
    const char* pa = (const char*)sA[c];
    const char* pb = (const char*)sB[c];
    s16x8 bfr[4][2];
#pragma unroll
    for (int n = 0; n < 4; ++n)
#pragma unroll
      for (int kk = 0; kk < 2; ++kk)
        bfr[n][kk] = *(const s16x8*)(pb + (size_t)(brow + n * 16) * 128 + ((kk * 64 + kb) ^ frswz));
#pragma unroll
    for (int ph = 0; ph < 4; ++ph) {
      s16x8 afr[2];
#pragma unroll
      for (int kk = 0; kk < 2; ++kk)
        afr[kk] = *(const s16x8*)(pa + (size_t)(arow + ph * 16) * 128 + ((kk * 64 + kb) ^ frswz));
      __builtin_amdgcn_s_setprio(1);
#pragma unroll
      for (int n = 0; n < 4; ++n)
#pragma unroll
        for (int kk = 0; kk < 2; ++kk)
          acc[ph][n] = __builtin_amdgcn_mfma_f32_16x16x32_bf16(
              afr[kk], bfr[n][kk], acc[ph][n], 0, 0, 0);
      __builtin_amdgcn_s_setprio(0);
    }
    __builtin_amdgcn_s_barrier();
    if (t + 2 < NT) { STAGE_A(sA[c], (t + 2) * 64); STAGE_B(sB[c], (t + 2) * 64); }
  }
#undef STAGE_A
#undef STAGE_B

  const int r0 = by * 256 + wm * 64 + ((ln >> 4) << 2);
  const int c0 = bx * 256 + wn * 64 + (ln & 15);
#pragma unroll
  for (int m = 0; m < 4; ++m)
#pragma unroll
    for (int n = 0; n < 4; ++n)
#pragma unroll
      for (int j = 0; j < 4; ++j) {
        int row = r0 + m * 16 + j, col = c0 + n * 16;
        if (OUTBF)
          ((u16*)Cp)[(size_t)row * ldc + col] = f2bf(acc[m][n][j]);
        else
          ((float*)Cp)[(size_t)row * ldc + col] = acc[m][n][j];
      }
}

// ---------------------------------------------------------------------------
// Generic batched GEMM (128x128 tile) — unchanged proven kernel.
// ---------------------------------------------------------------------------
template <int OUTBF>
__global__ __launch_bounds__(256) void gemm_bt(
    const u16* __restrict__ A, const u16* __restrict__ B, void* __restrict__ Cp,
    int K, int lda, int ldb, int ldc,
    long sAb, long sBb, long sCb1, long sCb2, int CZ2, int cmode, int swz)
{
  int bx = blockIdx.x, by = blockIdx.y;
  if (swz) {
    int nx = gridDim.x;
    int fid = by * nx + bx;
    int cpx = (nx * gridDim.y) >> 3;
    int nid = (fid & 7) * cpx + (fid >> 3);
    bx = nid % nx; by = nid / nx;
  }
  if (cmode == 1 && bx > by) return;
  __shared__ u16 sA[128 * 64];
  __shared__ u16 sB[128 * 64];
  const int tid = threadIdx.x, wv = tid >> 6, ln = tid & 63;
  const int z = blockIdx.z;
  const u16* Ab = A + (size_t)z * sAb + (size_t)(by * 128) * lda;
  const u16* Bb = B + (size_t)z * sBb + (size_t)(bx * 128) * ldb;
  const int wr = (wv >> 1) * 64, wc = (wv & 1) * 64;
  const int Keff = (cmode == 2) ? min(K, (by + 1) * 128) : K;

  f32x4 acc[4][4];
#pragma unroll
  for (int m = 0; m < 4; ++m)
#pragma unroll
    for (int n = 0; n < 4; ++n) {
      f32x4 zz = {0.f, 0.f, 0.f, 0.f};
      acc[m][n] = zz;
    }

  int o_[4], r_[4], cb_[4];
#pragma unroll
  for (int i = 0; i < 4; ++i) {
    int o = (wv * 4 + i) * 1024 + ln * 16;
    o_[i] = o;
    int r = o >> 7;
    r_[i] = r;
    cb_[i] = (o & 127) ^ ((r & 7) << 4);
  }
  const int frswz = (ln & 7) << 4;
  const int fkcol = (ln >> 4) << 4;

  for (int k0 = 0; k0 < Keff; k0 += 64) {
    __syncthreads();
#pragma unroll
    for (int i = 0; i < 4; ++i)
      gload16(Ab + (size_t)r_[i] * lda + (k0 + (cb_[i] >> 1)), (char*)sA + o_[i]);
#pragma unroll
    for (int i = 0; i < 4; ++i)
      gload16(Bb + (size_t)r_[i] * ldb + (k0 + (cb_[i] >> 1)), (char*)sB + o_[i]);
    __syncthreads();

#pragma unroll
    for (int ks = 0; ks < 2; ++ks) {
      s16x8 av[4], bv[4];
#pragma unroll
      for (int m = 0; m < 4; ++m) {
        int row = wr + m * 16 + (ln & 15);
        int addr = row * 128 + ((ks * 64 + fkcol) ^ frswz);
        av[m] = *(const s16x8*)((const char*)sA + addr);
      }
#pragma unroll
      for (int n = 0; n < 4; ++n) {
        int row = wc + n * 16 + (ln & 15);
        int addr = row * 128 + ((ks * 64 + fkcol) ^ frswz);
        bv[n] = *(const s16x8*)((const char*)sB + addr);
      }
#pragma unroll
      for (int m = 0; m < 4; ++m)
#pragma unroll
        for (int n = 0; n < 4; ++n)
          acc[m][n] = __builtin_amdgcn_mfma_f32_16x16x32_bf16(av[m], bv[n], acc[m][n], 0, 0, 0);
    }
  }

  const size_t cbase = (size_t)(z / CZ2) * sCb1 + (size_t)(z % CZ2) * sCb2;
  const int r0 = by * 128 + wr + ((ln >> 4) << 2);
  const int c0 = bx * 128 + wc + (ln & 15);
#pragma unroll
  for (int m = 0; m < 4; ++m)
#pragma unroll
    for (int n = 0; n < 4; ++n)
#pragma unroll
      for (int j = 0; j < 4; ++j) {
        int row = r0 + m * 16 + j, col = c0 + n * 16;
        if (OUTBF)
          ((u16*)Cp)[cbase + (size_t)row * ldc + col] = f2bf(acc[m][n][j]);
        else
          ((float*)Cp)[cbase + (size_t)row * ldc + col] = acc[m][n][j];
      }
}

// ---------------------------------------------------------------------------
// Transpose (batched): dst[z][c][r] = src[z1*sSrc1+z2*sSrc2 + r*srcLd + c]
// INBF=0: f32 source; INBF=1: bf16 source. Output bf16, rows padded to Cpad.
// ---------------------------------------------------------------------------
template <int INBF>
__global__ __launch_bounds__(256) void transpose_to_bf16(
    const void* __restrict__ srcv, u16* __restrict__ dst,
    int R, int C, int Cpad, int srcLd, long sSrc1, long sSrc2, int Z2, long sDst)
{
  __shared__ float tile[32][33];
  const int z = blockIdx.z, z1 = z / Z2, z2 = z % Z2;
  const size_t sbase = (size_t)z1 * sSrc1 + (size_t)z2 * sSrc2;
  u16* d = dst + (size_t)z * sDst;
  const int c0 = blockIdx.x * 32, r0 = blockIdx.y * 32;
  const int tx = threadIdx.x, ty = threadIdx.y;
#pragma unroll
  for (int i = 0; i < 4; ++i) {
    int r = r0 + ty + i * 8, c = c0 + tx;
    float v = 0.f;
    if (c < C && r < R) {
      if (INBF) v = bf2f(((const u16*)srcv)[sbase + (size_t)r * srcLd + c]);
      else      v = ((const float*)srcv)[sbase + (size_t)r * srcLd + c];
    }
    tile[ty + i * 8][tx] = v;
  }
  __syncthreads();
#pragma unroll
  for (int i = 0; i < 4; ++i) {
    int dr = c0 + ty + i * 8, dc = r0 + tx;
    if (dr < Cpad && dc < R) d[(size_t)dr * R + dc] = f2bf(tile[tx][ty + i * 8]);
  }
}

__global__ void cvt_f32_bf16_k(const float* __restrict__ src, u16* __restrict__ dst, int n4) {
  int i = blockIdx.x * 256 + threadIdx.x;
  if (i >= n4) return;
  const float4 v = ((const float4*)src)[i];
  u16* o = dst + (size_t)i * 4;
  o[0] = f2bf(v.x); o[1] = f2bf(v.y); o[2] = f2bf(v.z); o[3] = f2bf(v.w);
}

// RoPE from bf16 qkvm (row stride 6912): reads split halves, writes interleaved.
__global__ __launch_bounds__(256) void rope_k(
    const u16* __restrict__ qkvm, const float* __restrict__ fc,
    u16* __restrict__ qb, u16* __restrict__ kb)
{
  const int bt = blockIdx.x, b = bt >> 10, t = bt & 1023;
  const u16* row = qkvm + (size_t)bt * 6912;
  const float SC = 0.08838834764831845f;  // 128^-0.5
#pragma unroll
  for (int it = 0; it < 4; ++it) {
    int idx = threadIdx.x + it * 256;
    int h = idx >> 6, j = idx & 63;
    float c = fc[(t * 64 + j) * 2], sn = fc[(t * 64 + j) * 2 + 1];
    float qa = bf2f(row[h * 128 + j]), qbv = bf2f(row[h * 128 + 64 + j]);
    float ka = bf2f(row[2048 + h * 128 + j]), kbv = bf2f(row[2048 + h * 128 + 64 + j]);
    size_t o = ((size_t)(b * 16 + h) * 1024 + t) * 128 + 2 * j;
    qb[o]     = f2bf((qa * c - qbv * sn) * SC);
    qb[o + 1] = f2bf((qbv * c + qa * sn) * SC);
    kb[o]     = f2bf(ka * c - kbv * sn);
    kb[o + 1] = f2bf(kbv * c + ka * sn);
  }
}

// gelu in-place on bf16 hidden cols 6144..6655 of qkvm rows (stride 6912)
__global__ __launch_bounds__(64) void gelu_bf16_k(u16* __restrict__ qm) {
  int bt = blockIdx.x, tid = threadIdx.x;
  u16* p = qm + (size_t)bt * 6912 + 6144 + tid * 8;
  u16x8 v = *(u16x8*)p;
#pragma unroll
  for (int i = 0; i < 8; ++i) {
    float f = bf2f(v[i]);
    f = 0.5f * f * (1.f + erff(f * 0.70710678118654752f));
    v[i] = f2bf(f);
  }
  *(u16x8*)p = v;
}

// w = einsum(hid[bt,c,k], qkw[c,k,i,m]); w1 rms-normed over m. One wave per bt.
__global__ __launch_bounds__(64) void wproj_k(
    const u16* __restrict__ qkvm, const float* __restrict__ qkw,
    float* __restrict__ w1a, float* __restrict__ w2a, float* __restrict__ kpT)
{
  const int bt = blockIdx.x, ln = threadIdx.x;
  const int c = ln >> 4, m = ln & 15;
  const int b = bt >> 10, t = bt & 1023;
  const u16* hp = qkvm + (size_t)bt * 6912 + 6144 + c * 128;
  const float* Wp = qkw + (size_t)c * 4096 + m;
  float w1 = 0.f, w2 = 0.f;
  for (int k = 0; k < 128; ++k) {
    float hv = bf2f(hp[k]);
    w1 += hv * Wp[k * 32];
    w2 += hv * Wp[k * 32 + 16];
  }
  float ss = w1 * w1;
  ss += __shfl_xor(ss, 1); ss += __shfl_xor(ss, 2);
  ss += __shfl_xor(ss, 4); ss += __shfl_xor(ss, 8);
  float nrm = rsqrtf(ss * (1.f / 16.f) + 1e-6f);
  float w1n = w1 * nrm;
  size_t o = (size_t)bt * 64 + c * 16 + m;
  w1a[o] = w1n;
  w2a[o] = w2;
  size_t kb = (size_t)b * 98304 + (size_t)m * 1024 + t;
  if (c == 1) { kpT[kb] = w1n; kpT[kb + 16384] = w2; }
  if (c == 3) { kpT[kb + 49152] = w1n; kpT[kb + 65536] = w2; }
}

// dd from bf16 cols 6656..6719 of qkvm (stride 6912)
__global__ __launch_bounds__(64) void dd_k(const u16* __restrict__ qkvm,
                                           float* __restrict__ dda, float* __restrict__ kpT) {
  int bt = blockIdx.x, ln = threadIdx.x;
  int c = ln >> 4, m = ln & 15;
  int b = bt >> 10, t = bt & 1023;
  float v = tanhf(bf2f(qkvm[(size_t)bt * 6912 + 6656 + ln]));
  dda[(size_t)bt * 64 + ln] = v;
  size_t kb = (size_t)b * 98304 + (size_t)m * 1024 + t;
  if (c == 1) kpT[kb + 32768] = v;
  if (c == 3) kpT[kb + 81920] = v;
}

// ---------------------------------------------------------------------------
// Fused: preproj(cross-head) -> causal mask -> softmax (no max; logits O(15))
// -> postproj -> P(bf16). L bf16. One block per (b,t); 512 threads x
// 2 s-cols x 16 heads. Sum-reduce: wave-local LDS transpose (stride-17 pad,
// conflict-free) + 2 shfl. P stores skipped for s0 >= (t/128+1)*128.
// ---------------------------------------------------------------------------
__global__ __launch_bounds__(512, 4) void proj_softmax_k(
    const u16* __restrict__ L, u16* __restrict__ P,
    const float* __restrict__ w1a, const float* __restrict__ w2a,
    const float* __restrict__ dda, const float* __restrict__ kparT)
{
  const int t = blockIdx.x, b = blockIdx.y;
  const int tid = threadIdx.x, wv = tid >> 6, ln = tid & 63;
  const int s0 = tid * 2;
  const bool live = (s0 <= t);
  const int sKeff = (t & ~127) + 128;   // PV reads s in [0, sKeff)

  __shared__ float tbuf[8][64][17];     // stride-17: scalar ds ops conflict-free
  __shared__ float qpar[6][16];
  __shared__ float red2[16][8];
  __shared__ float rzf[16];
  if (tid < 96) {
    int a = tid >> 4, hh = tid & 15;
    const float* sp = (a == 0 || a == 3) ? w1a : ((a == 1 || a == 4) ? w2a : dda);
    int cc = (a < 3) ? 0 : 2;
    qpar[a][hh] = sp[(size_t)(b * 1024 + t) * 64 + cc * 16 + hh];
  }
  __syncthreads();

  const float* kp = kparT + (size_t)b * 98304 + s0;
  float v[16][2];
  const size_t lbase = ((size_t)(b * 16) * 1024 + t) * 1024 + s0;

  if (live) {
#pragma unroll
    for (int h = 0; h < 16; ++h) {
      u16x2 d = *(const u16x2*)(L + lbase + (size_t)h * 1048576);
      v[h][0] = bf2f(d[0]); v[h][1] = bf2f(d[1]);
    }
    float dq0 = 0.f, dq1 = 0.f, dk0 = 0.f, dk1 = 0.f;
#pragma unroll
    for (int h = 0; h < 16; ++h) {
      f32x2 k1 = *(const f32x2*)(kp + h * 1024);
      dq0 += v[h][0] * qpar[0][h]; dq1 += v[h][1] * qpar[0][h];
      dk0 += v[h][0] * k1[0];      dk1 += v[h][1] * k1[1];
    }
    const bool ok1 = (s0 + 1 <= t);
#pragma unroll
    for (int h = 0; h < 16; ++h) {
      f32x2 k2 = *(const f32x2*)(kp + 16384 + h * 1024);
      f32x2 kd = *(const f32x2*)(kp + 32768 + h * 1024);
      float a0 = v[h][0] * (1.f + qpar[2][h] + kd[0]) + qpar[1][h] * dq0 + k2[0] * dk0;
      float a1 = v[h][1] * (1.f + qpar[2][h] + kd[1]) + qpar[1][h] * dq1 + k2[1] * dk1;
      v[h][0] = __expf(a0);
      v[h][1] = ok1 ? __expf(a1) : 0.f;
    }
  }

  // wave-local LDS transpose reduce (same-wave ds ordering; no barrier).
  {
    float* tb = &tbuf[wv][ln][0];
#pragma unroll
    for (int h = 0; h < 16; ++h)
      tb[h] = live ? (v[h][0] + v[h][1]) : 0.f;
    int hh = ln & 15, q = ln >> 4;
    float sum = 0.f;
#pragma unroll
    for (int k = 0; k < 16; ++k) sum += tbuf[wv][q * 16 + k][hh];
    sum += __shfl_xor(sum, 16);
    sum += __shfl_xor(sum, 32);
    if (ln < 16) red2[ln][wv] = sum;
  }
  __syncthreads();
  if (tid < 16)
    rzf[tid] = 1.f / (((red2[tid][0] + red2[tid][1]) + (red2[tid][2] + red2[tid][3])) +
                      ((red2[tid][4] + red2[tid][5]) + (red2[tid][6] + red2[tid][7])));
  __syncthreads();

  if (s0 >= sKeff) return;   // PV never reads this region (no barriers below)

  // post-projection + store P (bf16). Masked -> exactly 0.
  const size_t pbase = ((size_t)(b * 16) * 1024 + t) * 1024 + s0;
  if (live) {
    float pdq0 = 0.f, pdq1 = 0.f, pdk0 = 0.f, pdk1 = 0.f;
#pragma unroll
    for (int h = 0; h < 16; ++h) {
      float rz = rzf[h];
      f32x2 k1 = *(const f32x2*)(kp + 49152 + h * 1024);
      float p0 = v[h][0] * rz, p1 = v[h][1] * rz;
      v[h][0] = p0; v[h][1] = p1;
      pdq0 += p0 * qpar[3][h]; pdq1 += p1 * qpar[3][h];
      pdk0 += p0 * k1[0];      pdk1 += p1 * k1[1];
    }
#pragma unroll
    for (int h = 0; h < 16; ++h) {
      f32x2 k2 = *(const f32x2*)(kp + 65536 + h * 1024);
      f32x2 kd = *(const f32x2*)(kp + 81920 + h * 1024);
      u16x2 pk;
      pk[0] = f2bf(v[h][0] * (1.f + qpar[5][h] + kd[0]) + qpar[4][h] * pdq0 + k2[0] * pdk0);
      pk[1] = f2bf(v[h][1] * (1.f + qpar[5][h] + kd[1]) + qpar[4][h] * pdq1 + k2[1] * pdk1);
      *(u16x2*)(P + pbase + (size_t)h * 1048576) = pk;
    }
  } else {
    u16x2 z2 = {0, 0};
#pragma unroll
    for (int h = 0; h < 16; ++h)
      *(u16x2*)(P + pbase + (size_t)h * 1048576) = z2;
  }
}

// ---------------------------------------------------------------------------
extern "C" void kernel_launch(void* const* d_in, const int* in_sizes, int n_in,
                              void* d_out, int out_size, void* d_ws, size_t ws_size,
                              hipStream_t stream)
{
  (void)in_sizes; (void)n_in; (void)out_size; (void)ws_size;
  const float* x    = (const float*)d_in[0];
  const float* fc   = (const float*)d_in[2];
  const float* wqkv = (const float*)d_in[3];
  const float* wo   = (const float*)d_in[4];
  const float* dw1  = (const float*)d_in[5];
  const float* qkw  = (const float*)d_in[6];
  const float* ddw  = (const float*)d_in[7];
  float* out = (float*)d_out;
  char* w = (char*)d_ws;

  // persistent region
  u16*   woT   = (u16*)(w + 0);
  u16*   qb    = (u16*)(w + 8388608);
  u16*   kb    = (u16*)(w + 16777216);
  u16*   vT    = (u16*)(w + 25165824);
  u16*   obf   = (u16*)(w + 33554432);
  float* w1a   = (float*)(w + 41943040);
  float* w2a   = (float*)(w + 42467328);
  float* dda   = (float*)(w + 42991616);
  const size_t TB = 43515904;
  // transient layout A (dead before attention phase)
  u16*   xb    = (u16*)(w + TB);                       // 8 MB
  u16*   wallT = (u16*)(w + TB + 8388608);             // [6912][2048] bf16 = 28.3 MB
  u16*   qkvm  = (u16*)(w + TB + 36700160);            // [2048][6912] bf16 = 28.3 MB
  // transient layout B (attention) overlays layout A
  u16*   L     = (u16*)(w + TB);                       // bf16 logits, 64 MB
  u16*   P     = (u16*)(w + TB + 67108864);            // bf16 probs, 64 MB
  float* kparT = (float*)(w + 244842496);              // 768 KiB
  // total ws need: 245,628,928 bytes

  // input converts / transposes (to bf16, B^T layouts; wqkv|dw1|ddw merged,
  // ddw segment zero-padded to row 6912 via Cpad=256)
  cvt_f32_bf16_k<<<4096, 256, 0, stream>>>(x, xb, 1048576);
  transpose_to_bf16<0><<<dim3(192, 64, 1), dim3(32, 8), 0, stream>>>(wqkv, wallT, 2048, 6144, 6144, 6144, 0, 0, 1, 0);
  transpose_to_bf16<0><<<dim3(16, 64, 1),  dim3(32, 8), 0, stream>>>(dw1,  wallT + (size_t)6144 * 2048, 2048, 512, 512, 512, 0, 0, 1, 0);
  transpose_to_bf16<0><<<dim3(8, 64, 1),   dim3(32, 8), 0, stream>>>(ddw,  wallT + (size_t)6656 * 2048, 2048, 64, 256, 64, 0, 0, 1, 0);
  transpose_to_bf16<0><<<dim3(64, 64, 1),  dim3(32, 8), 0, stream>>>(wo,   woT, 2048, 2048, 2048, 2048, 0, 0, 1, 0);

  // merged qkv|hidden|ddraw GEMM (M=2048, N=6912, K=2048; 256^2 pipelined)
  gemm256<1><<<dim3(27, 8, 1), 1024, 0, stream>>>(xb, wallT, qkvm, 2048, 2048, 2048, 6912);
  rope_k<<<2048, 256, 0, stream>>>(qkvm, fc, qb, kb);
  transpose_to_bf16<1><<<dim3(4, 32, 32), dim3(32, 8), 0, stream>>>(qkvm + 4096, vT, 1024, 128, 128, 6912, 7077888, 128, 16, 131072);

  // dynamic-compose weights from merged buffer
  gelu_bf16_k<<<2048, 64, 0, stream>>>(qkvm);
  wproj_k<<<2048, 64, 0, stream>>>(qkvm, qkw, w1a, w2a, kparT);
  dd_k<<<2048, 64, 0, stream>>>(qkvm, dda, kparT);

  // attention (L in bf16)
  gemm_bt<1><<<dim3(8, 8, 32), 256, 0, stream>>>(qb, kb, L, 128, 128, 128, 1024, 131072, 131072, 1048576, 0, 1, 1, 0);
  proj_softmax_k<<<dim3(1024, 2, 1), 512, 0, stream>>>(L, P, w1a, w2a, dda, kparT);
  gemm_bt<1><<<dim3(1, 8, 32), 256, 0, stream>>>(P, vT, obf, 1024, 1024, 1024, 2048, 1048576, 131072, 2097152, 128, 16, 2, 0);

  // out = o @ wo (XCD-swizzled, 128^2)
  gemm_bt<0><<<dim3(16, 16, 1), 256, 0, stream>>>(obf, woT, out, 2048, 2048, 2048, 2048, 0, 0, 0, 0, 1, 0, 1);
}